// Round 8
// baseline (279.588 us; speedup 1.0000x reference)
//
#include <hip/hip_runtime.h>

// GRU (B=4096, T=512, I=1, H=32) + FC(32->12): single-wave MFMA, zero barriers.
//
// 256 blocks x 64 threads (ONE wave) = 1 block/CU; block owns 16 batch rows.
// Key fact (validated by round 7's passing absmax): for mfma_f32_16x16x16f16,
// lane L holds D[i = 4*(L>>4)+reg][j = L&15]. With 6 B-tiles (r0,r1,z0,z1,n0,n1)
// lane L ends each step holding the COMPLETE r/z/n preactivations for
// units {L&15, (L&15)+16} x rows 4*(L>>4)+{0..3} = 8 h-updates, entirely in
// registers. So one wave does MFMA AND gates: no barriers, no preact LDS.
// Per-step LDS = only the h redistribution into A-fragment layout
// (8x ds_write_b16 + 2x ds_read_b64, kHP=36 -> conflict-free writes).
// h kept f32 in registers (recurrence never rounded); f16 only for MFMA A.
// exp folding: r,z weight rows scaled by -log2e, n rows by +2log2e, so gates
// use raw v_exp_f32 (2^x) + v_rcp.

namespace {

typedef _Float16 f16;
typedef _Float16 f16x4 __attribute__((ext_vector_type(4)));
typedef float    f32x4 __attribute__((ext_vector_type(4)));

constexpr int kT  = 512;
constexpr int kXP = 516;   // xs row pitch (f32)
constexpr int kHP = 36;    // hl row pitch (f16): 72B rows, 8B-aligned b64 frags
constexpr float kL2E = 1.4426950408889634f;

__device__ __forceinline__ float fast_exp2(float a) {
#if __has_builtin(__builtin_amdgcn_exp2f)
    return __builtin_amdgcn_exp2f(a);
#else
    return exp2f(a);
#endif
}
__device__ __forceinline__ float fast_rcp(float a) {
#if __has_builtin(__builtin_amdgcn_rcpf)
    return __builtin_amdgcn_rcpf(a);
#else
    return 1.0f / a;
#endif
}

__global__ __launch_bounds__(64)
__attribute__((amdgpu_waves_per_eu(1, 1)))
void gru_mfma1(
    const float* __restrict__ x,      // [4096, 512]
    const float* __restrict__ w_ih,   // [96]
    const float* __restrict__ w_hh,   // [96, 32]
    const float* __restrict__ b_ih,   // [96]
    const float* __restrict__ b_hh,   // [96]
    const float* __restrict__ fc_w,   // [12, 32]
    const float* __restrict__ fc_b,   // [12]
    float* __restrict__ out)          // [4096, 12]
{
    __shared__ float xs[16 * kXP];    // staged x (reused as hf[16][33] at end)
    __shared__ f16   hl[16 * kHP];    // f16 h in A-operand layout

    const int lane = threadIdx.x;     // 0..63 (single wave)
    const int lc   = lane & 15;
    const int lg   = lane >> 4;
    const int blk  = blockIdx.x;

    // ---- stage x: block's 16 rows = one contiguous 32KB chunk ----
    {
        const float4* xg = reinterpret_cast<const float4*>(x + (size_t)blk * 16 * kT);
#pragma unroll
        for (int k = 0; k < 32; ++k) {
            const int i = lane + k * 64;        // float4 index over 2048
            const float4 v = xg[i];
            const int row = i >> 7;
            const int col = (i & 127) << 2;
            *reinterpret_cast<float4*>(&xs[row * kXP + col]) = v;
        }
    }

    // ---- MFMA B-fragments (w_hh^T), scale-folded (validated R7 layout):
    //      B[k = 4*lg + v][col = lc] ; tiles: 0,1=r 2,3=z 4,5=n ----
    f16x4 wf[6][2];
#pragma unroll
    for (int nt = 0; nt < 6; ++nt) {
        const float s = (nt < 4) ? -kL2E : 2.0f * kL2E;
#pragma unroll
        for (int kt = 0; kt < 2; ++kt) {
            f16x4 f;
#pragma unroll
            for (int v = 0; v < 4; ++v)
                f[v] = (f16)(s * w_hh[((nt >> 1) * 32 + (nt & 1) * 16 + lc) * 32 +
                                      kt * 16 + lg * 4 + v]);
            wf[nt][kt] = f;
        }
    }

    // ---- gate constants for this lane's two units u = lc, lc+16 ----
    float wihr[2], wihz[2], wihn[2], biasr[2], biasz[2], binn[2], bhnn[2];
#pragma unroll
    for (int q = 0; q < 2; ++q) {
        const int u = lc + q * 16;
        wihr[q]  = -kL2E * w_ih[u];
        wihz[q]  = -kL2E * w_ih[u + 32];
        wihn[q]  = 2.0f * kL2E * w_ih[u + 64];
        biasr[q] = -kL2E * (b_ih[u] + b_hh[u]);
        biasz[q] = -kL2E * (b_ih[u + 32] + b_hh[u + 32]);
        binn[q]  = 2.0f * kL2E * b_ih[u + 64];
        bhnn[q]  = 2.0f * kL2E * b_hh[u + 64];
    }

    // h state: h[q][v] = h[row 4*lg+v][unit lc+16q], f32, never rounded
    float h[2][4] = {{0, 0, 0, 0}, {0, 0, 0, 0}};
    // A-fragments for t=0: h0 = 0
    f16x4 a0 = {(f16)0, (f16)0, (f16)0, (f16)0};
    f16x4 a1 = a0;

    for (int t = 0; t < kT; ++t) {
        // ---- MFMA: preact[16 rows x 96 gates] (6 acc chains of 2) ----
        f32x4 acc[6];
#pragma unroll
        for (int nt = 0; nt < 6; ++nt) {
            f32x4 c = {0.0f, 0.0f, 0.0f, 0.0f};
            c = __builtin_amdgcn_mfma_f32_16x16x16f16(a0, wf[nt][0], c, 0, 0, 0);
            c = __builtin_amdgcn_mfma_f32_16x16x16f16(a1, wf[nt][1], c, 0, 0, 0);
            acc[nt] = c;
        }

        // x for rows 4*lg + v (broadcast among the 16 lanes sharing lg)
        float xt[4];
#pragma unroll
        for (int v = 0; v < 4; ++v) xt[v] = xs[(4 * lg + v) * kXP + t];

        // ---- gates: 8 updates, all inputs in registers ----
#pragma unroll
        for (int v = 0; v < 4; ++v) {
#pragma unroll
            for (int q = 0; q < 2; ++q) {
                const float ar = acc[0 + q][v] + fmaf(xt[v], wihr[q], biasr[q]);
                const float az = acc[2 + q][v] + fmaf(xt[v], wihz[q], biasz[q]);
                const float an = acc[4 + q][v] + bhnn[q];
                const float inn = fmaf(xt[v], wihn[q], binn[q]);
                const float r = fast_rcp(1.0f + fast_exp2(ar));
                const float z = fast_rcp(1.0f + fast_exp2(az));
                const float n = fmaf(-2.0f,
                    fast_rcp(1.0f + fast_exp2(fmaf(r, an, inn))), 1.0f);
                h[q][v] = fmaf(z, h[q][v] - n, n);
                // publish f16 h into A layout: hl[row][unit]
                hl[(4 * lg + v) * kHP + lc + q * 16] = (f16)h[q][v];
            }
        }

        // ---- next A-fragments (same wave: DS pipe is in-order) ----
        a0 = *reinterpret_cast<const f16x4*>(&hl[lc * kHP + lg * 4]);
        a1 = *reinterpret_cast<const f16x4*>(&hl[lc * kHP + 16 + lg * 4]);
    }

    // ---- FC epilogue: hf (f32, pitch 33) in reused xs ----
    float* hf = xs;
#pragma unroll
    for (int v = 0; v < 4; ++v) {
        hf[(4 * lg + v) * 33 + lc]      = h[0][v];
        hf[(4 * lg + v) * 33 + lc + 16] = h[1][v];
    }
    // single wave: writes above are visible to the reads below (in-order DS)
#pragma unroll
    for (int p = 0; p < 3; ++p) {
        const int idx = lane + p * 64;        // 0..191 = 16 rows x 12 outs
        const int row = idx / 12, o = idx % 12;
        float acc = fc_b[o];
#pragma unroll
        for (int k = 0; k < 32; ++k)
            acc = fmaf(fc_w[o * 32 + k], hf[row * 33 + k], acc);
        out[((size_t)blk * 16 + row) * 12 + o] = acc;
    }
}

}  // namespace

extern "C" void kernel_launch(void* const* d_in, const int* in_sizes, int n_in,
                              void* d_out, int out_size, void* d_ws, size_t ws_size,
                              hipStream_t stream) {
    const float* x    = (const float*)d_in[0];
    const float* w_ih = (const float*)d_in[1];
    const float* w_hh = (const float*)d_in[2];
    const float* b_ih = (const float*)d_in[3];
    const float* b_hh = (const float*)d_in[4];
    const float* fc_w = (const float*)d_in[5];
    const float* fc_b = (const float*)d_in[6];
    float* out = (float*)d_out;

    dim3 grid(256);   // 4096 rows / 16 per block
    dim3 block(64);   // one wave: MFMA + gates, zero barriers
    gru_mfma1<<<grid, block, 0, stream>>>(x, w_ih, w_hh, b_ih, b_hh, fc_w, fc_b, out);
}

// Round 9
// 218.774 us; speedup vs baseline: 1.2780x; 1.2780x over previous
//
#include <hip/hip_runtime.h>

// GRU (B=4096, T=512, I=1, H=32) + FC(32->12): register-resident recurrence.
//
// 256 blocks x 64 threads (1 wave, 1 block/CU); block owns 16 batch rows.
// MFMA operands SWAPPED vs rounds 7/8: A = w_hh tiles (constant, registers),
// B = h^T. With the validated gfx950 16x16x16f16 layouts
//   A[row=L&15][k=4*(L>>4)+i], B[k=4*(L>>4)+i][col=L&15],
//   D[i=4*(L>>4)+v][j=L&15],
// D gives lane L the preacts for row lc = L&15, units {4lg+v, 16+4lg+v}
// (lg=L>>4), and the gate outputs lane L computes are EXACTLY the B-fragment
// it must supply next step: h[row lc][unit 4lg+i] (k-tile 0) and
// h[row lc][unit 16+4lg+i] (k-tile 1). The recurrence lives entirely in
// registers: ZERO LDS, zero barriers, zero cross-lane ops in the T-loop
// (round 8 showed 1100 cy/step of pure LDS/latency stall on this path).
// x: lane L only needs row lc -> direct global float4 per 4 steps,
// double-buffered (duplicate addresses across lg coalesce).
// Biases fold into the MFMA C operand (C input of the first MFMA per chain).
// h kept f32 in registers; f16 only as MFMA B operand (R7/R8-validated
// numerics, absmax ~1e-3). exp folding: r,z rows scaled by -log2e, n rows
// by +2log2e -> raw v_exp_f32 + v_rcp gates.

namespace {

typedef _Float16 f16;
typedef _Float16 f16x4 __attribute__((ext_vector_type(4)));
typedef float    f32x4 __attribute__((ext_vector_type(4)));

constexpr int kT = 512;
constexpr float kL2E = 1.4426950408889634f;

__device__ __forceinline__ float fast_exp2(float a) {
#if __has_builtin(__builtin_amdgcn_exp2f)
    return __builtin_amdgcn_exp2f(a);
#else
    return exp2f(a);
#endif
}
__device__ __forceinline__ float fast_rcp(float a) {
#if __has_builtin(__builtin_amdgcn_rcpf)
    return __builtin_amdgcn_rcpf(a);
#else
    return 1.0f / a;
#endif
}

__global__ __launch_bounds__(64)
__attribute__((amdgpu_waves_per_eu(1, 1)))
void gru_reg(
    const float* __restrict__ x,      // [4096, 512]
    const float* __restrict__ w_ih,   // [96]
    const float* __restrict__ w_hh,   // [96, 32]
    const float* __restrict__ b_ih,   // [96]
    const float* __restrict__ b_hh,   // [96]
    const float* __restrict__ fc_w,   // [12, 32]
    const float* __restrict__ fc_b,   // [12]
    float* __restrict__ out)          // [4096, 12]
{
    __shared__ float hf[16 * 33];     // FC epilogue only

    const int lane = threadIdx.x;     // single wave
    const int lc   = lane & 15;       // batch row owned (within tile)
    const int lg   = (lane >> 4) & 3;
    const int blk  = blockIdx.x;

    // ---- A-operand weight fragments: wA[gate][half][ktile], scale-folded.
    //      element i: w_s[gate*32 + half*16 + lc][ktile*16 + 4*lg + i] ----
    f16x4 wA[3][2][2];
#pragma unroll
    for (int g = 0; g < 3; ++g) {
        const float s = (g < 2) ? -kL2E : 2.0f * kL2E;
#pragma unroll
        for (int hh = 0; hh < 2; ++hh)
#pragma unroll
            for (int kt = 0; kt < 2; ++kt) {
                f16x4 f;
#pragma unroll
                for (int i = 0; i < 4; ++i)
                    f[i] = (f16)(s * w_hh[(g * 32 + hh * 16 + lc) * 32 +
                                          kt * 16 + 4 * lg + i]);
                wA[g][hh][kt] = f;
            }
    }

    // ---- bias C-operands and per-unit gate constants (8 units/lane) ----
    f32x4 biasC[3][2];                 // [gate][half], element v -> unit
    float cwr[2][4], cwz[2][4], cwn[2][4], cbn[2][4];
#pragma unroll
    for (int hh = 0; hh < 2; ++hh)
#pragma unroll
        for (int v = 0; v < 4; ++v) {
            const int u = hh * 16 + 4 * lg + v;
            biasC[0][hh][v] = -kL2E * (b_ih[u] + b_hh[u]);
            biasC[1][hh][v] = -kL2E * (b_ih[u + 32] + b_hh[u + 32]);
            biasC[2][hh][v] = 2.0f * kL2E * b_hh[u + 64];
            cwr[hh][v] = -kL2E * w_ih[u];
            cwz[hh][v] = -kL2E * w_ih[u + 32];
            cwn[hh][v] = 2.0f * kL2E * w_ih[u + 64];
            cbn[hh][v] = 2.0f * kL2E * b_ih[u + 64];
        }

    // ---- state: h (f32, never rounded) + f16 B-fragments ----
    float h[2][4] = {{0, 0, 0, 0}, {0, 0, 0, 0}};
    f16x4 B0 = {(f16)0, (f16)0, (f16)0, (f16)0};
    f16x4 B1 = B0;

    const float4* xrow = reinterpret_cast<const float4*>(
        x + ((size_t)blk * 16 + lc) * kT);

    float4 xcur = xrow[0];

    for (int t0 = 0; t0 < kT; t0 += 4) {
        const int nq = (t0 + 4 < kT) ? (t0 >> 2) + 1 : (t0 >> 2);
        float4 xnext = xrow[nq];

#pragma unroll
        for (int tt = 0; tt < 4; ++tt) {
            const float xt = (tt == 0) ? xcur.x : (tt == 1) ? xcur.y
                           : (tt == 2) ? xcur.z : xcur.w;

            // ---- 12 MFMA: preact tiles, bias pre-loaded via C operand ----
            f32x4 aR[2], aZ[2], aN[2];
#pragma unroll
            for (int hh = 0; hh < 2; ++hh) {
                f32x4 c;
                c = __builtin_amdgcn_mfma_f32_16x16x16f16(wA[0][hh][0], B0, biasC[0][hh], 0, 0, 0);
                aR[hh] = __builtin_amdgcn_mfma_f32_16x16x16f16(wA[0][hh][1], B1, c, 0, 0, 0);
                c = __builtin_amdgcn_mfma_f32_16x16x16f16(wA[1][hh][0], B0, biasC[1][hh], 0, 0, 0);
                aZ[hh] = __builtin_amdgcn_mfma_f32_16x16x16f16(wA[1][hh][1], B1, c, 0, 0, 0);
                c = __builtin_amdgcn_mfma_f32_16x16x16f16(wA[2][hh][0], B0, biasC[2][hh], 0, 0, 0);
                aN[hh] = __builtin_amdgcn_mfma_f32_16x16x16f16(wA[2][hh][1], B1, c, 0, 0, 0);
            }

            // ---- gates: 8 updates, all inputs in registers ----
#pragma unroll
            for (int hh = 0; hh < 2; ++hh) {
#pragma unroll
                for (int v = 0; v < 4; ++v) {
                    const float ar = fmaf(xt, cwr[hh][v], aR[hh][v]);
                    const float az = fmaf(xt, cwz[hh][v], aZ[hh][v]);
                    const float inn = fmaf(xt, cwn[hh][v], cbn[hh][v]);
                    const float r = fast_rcp(1.0f + fast_exp2(ar));
                    const float z = fast_rcp(1.0f + fast_exp2(az));
                    const float targ = fmaf(r, aN[hh][v], inn);
                    const float n = fmaf(-2.0f,
                        fast_rcp(1.0f + fast_exp2(targ)), 1.0f);
                    h[hh][v] = fmaf(z, h[hh][v] - n, n);
                }
            }

            // ---- next-step B fragments: pure register cvt ----
            f16x4 nb0, nb1;
#pragma unroll
            for (int v = 0; v < 4; ++v) {
                nb0[v] = (f16)h[0][v];
                nb1[v] = (f16)h[1][v];
            }
            B0 = nb0;
            B1 = nb1;
        }
        xcur = xnext;
    }

    // ---- FC epilogue (only LDS use): hf[row][unit], pitch 33 ----
#pragma unroll
    for (int hh = 0; hh < 2; ++hh)
#pragma unroll
        for (int v = 0; v < 4; ++v)
            hf[lc * 33 + hh * 16 + 4 * lg + v] = h[hh][v];
    __builtin_amdgcn_s_waitcnt(0);  // drain LDS writes (single wave, in-order)
#pragma unroll
    for (int p = 0; p < 3; ++p) {
        const int idx = lane + p * 64;      // 192 = 16 rows x 12 outs
        const int row = idx / 12, o = idx % 12;
        float acc = fc_b[o];
#pragma unroll
        for (int k = 0; k < 32; ++k)
            acc = fmaf(fc_w[o * 32 + k], hf[row * 33 + k], acc);
        out[((size_t)blk * 16 + row) * 12 + o] = acc;
    }
}

}  // namespace

extern "C" void kernel_launch(void* const* d_in, const int* in_sizes, int n_in,
                              void* d_out, int out_size, void* d_ws, size_t ws_size,
                              hipStream_t stream) {
    const float* x    = (const float*)d_in[0];
    const float* w_ih = (const float*)d_in[1];
    const float* w_hh = (const float*)d_in[2];
    const float* b_ih = (const float*)d_in[3];
    const float* b_hh = (const float*)d_in[4];
    const float* fc_w = (const float*)d_in[5];
    const float* fc_b = (const float*)d_in[6];
    float* out = (float*)d_out;

    dim3 grid(256);   // 4096 rows / 16 per block
    dim3 block(64);   // one wave: MFMA + gates, zero LDS in the loop
    gru_reg<<<grid, block, 0, stream>>>(x, w_ih, w_hh, b_ih, b_hh, fc_w, fc_b, out);
}

// Round 10
// 134.783 us; speedup vs baseline: 2.0744x; 1.6232x over previous
//
#include <hip/hip_runtime.h>

// GRU (B=4096, T=512, I=1, H=32) + FC(32->12): row-replicated MFMA + swizzle.
//
// 1024 blocks x 64 threads (1 wave each) -> 1024 waves = 1 per SIMD, ALL
// SIMDs of all CUs active. Each wave owns FOUR batch rows, replicated 4x
// into the MFMA B operand:  B[k][c = 4q + j] = h[row j][k]  (q = 0..3).
// With the validated 16x16x16f16 layouts (A[row=L&15][k=4(L>>4)+i],
// D[i=4(L>>4)+v][j=L&15]), lane L = (lg, c=4q+j) then holds preacts for
// row j, units {hh*16 + 4lg + v} replicated across q - so assigning each
// replica two units (hh = q>>1, v = 2(q&1)+{0,1}) spreads the gate
// transcendentals over ALL 64 lanes of ALL 1024 waves (round 9 showed the
// gate trans work concentrated on 256 waves was the ~600 cy/step floor).
// The next step's B fragment is rebuilt from the 2 per-lane h values with
// one f16 pack + 4 ds_swizzle_b32 (static patterns, register cross-lane):
// zero LDS, zero barriers, zero cross-wave traffic in the whole T-loop.
// h stays f32 in registers; f16 only as the MFMA B operand (validated
// numerics, absmax ~1e-3). exp folding: r,z rows scaled by -log2e, n rows
// by +2log2e -> raw v_exp_f32 + v_rcp gates.

namespace {

typedef _Float16 f16;
typedef _Float16 f16x2 __attribute__((ext_vector_type(2)));
typedef _Float16 f16x4 __attribute__((ext_vector_type(4)));
typedef float    f32x4 __attribute__((ext_vector_type(4)));

constexpr int kT = 512;
constexpr float kL2E = 1.4426950408889634f;

__device__ __forceinline__ float fast_exp2(float a) {
#if __has_builtin(__builtin_amdgcn_exp2f)
    return __builtin_amdgcn_exp2f(a);
#else
    return exp2f(a);
#endif
}
__device__ __forceinline__ float fast_rcp(float a) {
#if __has_builtin(__builtin_amdgcn_rcpf)
    return __builtin_amdgcn_rcpf(a);
#else
    return 1.0f / a;
#endif
}

union PK {
    f16x2 h2;
    int   i;
};
union B64 {
    int   i2[2];
    f16x4 v;
};

__global__ __launch_bounds__(64)
__attribute__((amdgpu_waves_per_eu(1, 1)))
void gru_swz(
    const float* __restrict__ x,      // [4096, 512]
    const float* __restrict__ w_ih,   // [96]
    const float* __restrict__ w_hh,   // [96, 32]
    const float* __restrict__ b_ih,   // [96]
    const float* __restrict__ b_hh,   // [96]
    const float* __restrict__ fc_w,   // [12, 32]
    const float* __restrict__ fc_b,   // [12]
    float* __restrict__ out)          // [4096, 12]
{
    __shared__ float hf[4 * 33];      // FC epilogue only

    const int lane = threadIdx.x;     // single wave
    const int c    = lane & 15;       // B column = 4q + j
    const int lg   = lane >> 4;       // k-group / D row-group
    const int q    = c >> 2;          // replica id -> which 2 units we own
    const int j    = c & 3;           // batch row owned (within block's 4)
    const int blk  = blockIdx.x;

    // ---- A-operand weight fragments (same as R9):
    //      A[row=c][k=kt*16+4lg+i] = w_hh[g*32+hh*16+c][...], scale-folded ----
    f16x4 wA[3][2][2];
#pragma unroll
    for (int g = 0; g < 3; ++g) {
        const float s = (g < 2) ? -kL2E : 2.0f * kL2E;
#pragma unroll
        for (int hh = 0; hh < 2; ++hh)
#pragma unroll
            for (int kt = 0; kt < 2; ++kt) {
                f16x4 f;
#pragma unroll
                for (int i = 0; i < 4; ++i)
                    f[i] = (f16)(s * w_hh[(g * 32 + hh * 16 + c) * 32 +
                                          kt * 16 + 4 * lg + i]);
                wA[g][hh][kt] = f;
            }
    }

    // ---- bias C-operands: C[i=4lg+v][*] = bias(unit hh*16+4lg+v) ----
    f32x4 biasC[3][2];
#pragma unroll
    for (int hh = 0; hh < 2; ++hh)
#pragma unroll
        for (int v = 0; v < 4; ++v) {
            const int u = hh * 16 + 4 * lg + v;
            biasC[0][hh][v] = -kL2E * (b_ih[u] + b_hh[u]);
            biasC[1][hh][v] = -kL2E * (b_ih[u + 32] + b_hh[u + 32]);
            biasC[2][hh][v] = 2.0f * kL2E * b_hh[u + 64];
        }

    // ---- this lane's two owned units: u0 = (q>>1)*16 + 4lg + 2(q&1), u0+1 ----
    const int u0 = (q >> 1) * 16 + 4 * lg + (q & 1) * 2;
    float cwr[2], cwz[2], cwn[2], cbn[2];
#pragma unroll
    for (int w = 0; w < 2; ++w) {
        const int u = u0 + w;
        cwr[w] = -kL2E * w_ih[u];
        cwz[w] = -kL2E * w_ih[u + 32];
        cwn[w] = 2.0f * kL2E * w_ih[u + 64];
        cbn[w] = 2.0f * kL2E * b_ih[u + 64];
    }

    // ---- state ----
    float h[2] = {0.0f, 0.0f};        // h[row j][u0], h[row j][u0+1], f32
    f16x4 B0 = {(f16)0, (f16)0, (f16)0, (f16)0};
    f16x4 B1 = B0;

    const float4* xrow = reinterpret_cast<const float4*>(
        x + ((size_t)blk * 4 + j) * kT);
    float4 xcur = xrow[0];

    const bool ql = (q & 1) != 0;     // selects v-pair {2,3} vs {0,1}
    const bool qh = (q >> 1) != 0;    // selects hh-tile 1 vs 0

    for (int t0 = 0; t0 < kT; t0 += 4) {
        const int nq = (t0 + 4 < kT) ? (t0 >> 2) + 1 : (t0 >> 2);
        float4 xnext = xrow[nq];

#pragma unroll
        for (int tt = 0; tt < 4; ++tt) {
            const float xt = (tt == 0) ? xcur.x : (tt == 1) ? xcur.y
                           : (tt == 2) ? xcur.z : xcur.w;

            // ---- 12 MFMA: replicated preacts, bias via C operand ----
            f32x4 aR[2], aZ[2], aN[2];
#pragma unroll
            for (int hh = 0; hh < 2; ++hh) {
                f32x4 cc;
                cc = __builtin_amdgcn_mfma_f32_16x16x16f16(wA[0][hh][0], B0, biasC[0][hh], 0, 0, 0);
                aR[hh] = __builtin_amdgcn_mfma_f32_16x16x16f16(wA[0][hh][1], B1, cc, 0, 0, 0);
                cc = __builtin_amdgcn_mfma_f32_16x16x16f16(wA[1][hh][0], B0, biasC[1][hh], 0, 0, 0);
                aZ[hh] = __builtin_amdgcn_mfma_f32_16x16x16f16(wA[1][hh][1], B1, cc, 0, 0, 0);
                cc = __builtin_amdgcn_mfma_f32_16x16x16f16(wA[2][hh][0], B0, biasC[2][hh], 0, 0, 0);
                aN[hh] = __builtin_amdgcn_mfma_f32_16x16x16f16(wA[2][hh][1], B1, cc, 0, 0, 0);
            }

            // ---- select this lane's 2 preact triples (compile-time comps) ----
            float prq[2], pzq[2], pnq[2];
#pragma unroll
            for (int w = 0; w < 2; ++w) {
                prq[w] = qh ? (ql ? aR[1][2 + w] : aR[1][w])
                            : (ql ? aR[0][2 + w] : aR[0][w]);
                pzq[w] = qh ? (ql ? aZ[1][2 + w] : aZ[1][w])
                            : (ql ? aZ[0][2 + w] : aZ[0][w]);
                pnq[w] = qh ? (ql ? aN[1][2 + w] : aN[1][w])
                            : (ql ? aN[0][2 + w] : aN[0][w]);
            }

            // ---- 2 gate updates ----
#pragma unroll
            for (int w = 0; w < 2; ++w) {
                const float ar  = fmaf(xt, cwr[w], prq[w]);
                const float az  = fmaf(xt, cwz[w], pzq[w]);
                const float inn = fmaf(xt, cwn[w], cbn[w]);
                const float r = fast_rcp(1.0f + fast_exp2(ar));
                const float z = fast_rcp(1.0f + fast_exp2(az));
                const float n = fmaf(-2.0f,
                    fast_rcp(1.0f + fast_exp2(fmaf(r, pnq[w], inn))), 1.0f);
                h[w] = fmaf(z, h[w] - n, n);
            }

            // ---- rebuild B fragments: 1 pack + 4 static ds_swizzle ----
            PK pk;
            pk.h2[0] = (f16)h[0];
            pk.h2[1] = (f16)h[1];
            // src lane = (lane & 0b10011) | (q'<<2): same lg, row j, replica q'
            const int s0 = __builtin_amdgcn_ds_swizzle(pk.i, 0x0013);  // q'=0
            const int s1 = __builtin_amdgcn_ds_swizzle(pk.i, 0x0093);  // q'=1
            const int s2 = __builtin_amdgcn_ds_swizzle(pk.i, 0x0113);  // q'=2
            const int s3 = __builtin_amdgcn_ds_swizzle(pk.i, 0x0193);  // q'=3
            B64 b0, b1;
            b0.i2[0] = s0; b0.i2[1] = s1;   // units 4lg+0..3   (k-tile 0)
            b1.i2[0] = s2; b1.i2[1] = s3;   // units 16+4lg+0..3 (k-tile 1)
            B0 = b0.v;
            B1 = b1.v;
        }
        xcur = xnext;
    }

    // ---- FC epilogue: assemble h[4][32] in LDS, 48 lanes compute outs ----
    hf[j * 33 + u0]     = h[0];
    hf[j * 33 + u0 + 1] = h[1];
    __syncthreads();
    if (lane < 48) {
        const int row = lane / 12, o = lane % 12;
        float acc = fc_b[o];
#pragma unroll
        for (int k = 0; k < 32; ++k)
            acc = fmaf(fc_w[o * 32 + k], hf[row * 33 + k], acc);
        out[((size_t)blk * 4 + row) * 12 + o] = acc;
    }
}

}  // namespace

extern "C" void kernel_launch(void* const* d_in, const int* in_sizes, int n_in,
                              void* d_out, int out_size, void* d_ws, size_t ws_size,
                              hipStream_t stream) {
    const float* x    = (const float*)d_in[0];
    const float* w_ih = (const float*)d_in[1];
    const float* w_hh = (const float*)d_in[2];
    const float* b_ih = (const float*)d_in[3];
    const float* b_hh = (const float*)d_in[4];
    const float* fc_w = (const float*)d_in[5];
    const float* fc_b = (const float*)d_in[6];
    float* out = (float*)d_out;

    dim3 grid(1024);  // 4096 rows / 4 per wave
    dim3 block(64);   // 1 wave per block -> 1 wave per SIMD chip-wide
    gru_swz<<<grid, block, 0, stream>>>(x, w_ih, w_hh, b_ih, b_hh, fc_w, fc_b, out);
}